// Round 6
// baseline (61.291 us; speedup 1.0000x reference)
//
#include <hip/hip_runtime.h>

// Gemma4VisionPooler: B=16, S=4096 (64x64 grid), H=1152, OUT=256, k=4.
// out[b,o,:] = (sum over the <=16 rows x[b,s,:] with bucket(s)==o) * sqrt(H)/16
// bucket = (px/k) + (max_x/k)*(py/k); pos clamped >=0; padding rows ([-1,-1])
// contribute zero (reference zeroes them before the segment-sum).
//
// Single fused kernel, 768 blocks (exactly 3/CU, fully co-resident):
// each block owns 3 consecutive 256-thread chunks of one batch, rebuilds the
// bucket->rows map once (pos scan, L2-resident), then gathers 3 chunks.

#define BB 16
#define SS 4096
#define HH 1152
#define OUTL 256
#define KK 4
#define K2 16
#define H4 (HH / 4)     // 288 float4 per row
#define HP (H4 / 2)     // 144 threads per output row, 2 rep-strided float4 each
#define GPB 48          // block-groups per batch (48 * 768 threads = 36864 = OUTL*HP)
#define NB 7            // max distinct output rows spanned by 768 threads

__global__ __launch_bounds__(256, 3) void pool_fused(const float* __restrict__ x,
                                                     const int* __restrict__ pos,
                                                     float* __restrict__ out) {
    int blk = blockIdx.x;
    int b = blk / GPB;
    int g = blk - b * GPB;            // group within batch: threads [g*768, g*768+768)
    int t = threadIdx.x;
    int base = g * 768;
    int lo = base / HP;               // first output row this block touches

    const int2* p2 = reinterpret_cast<const int2*>(pos) + (size_t)b * SS;

    // ---- prologue: register-cached scan of this batch's positions ----
    int2 rr[SS / 256];
#pragma unroll
    for (int i = 0; i < SS / 256; ++i) rr[i] = p2[t + i * 256];

    int m = 0;  // max px; padding px=-1 never beats 0
#pragma unroll
    for (int i = 0; i < SS / 256; ++i) m = max(m, rr[i].x);
#pragma unroll
    for (int o = 32; o > 0; o >>= 1) m = max(m, __shfl_down(m, o));

    __shared__ int wred[4];
    __shared__ int lrows[NB * K2];    // 112 ints
    if ((t & 63) == 0) wred[t >> 6] = m;
    if (t < NB * K2) lrows[t] = -1;
    __syncthreads();
    int mxk = (max(max(wred[0], wred[1]), max(wred[2], wred[3])) + 1) / KK;

    // deterministic slot = (py%4)*4 + (px%4): lists ascending by construction
#pragma unroll
    for (int i = 0; i < SS / 256; ++i) {
        int2 xy = rr[i];
        if (xy.x == -1 && xy.y == -1) continue;  // padding row -> zero contribution
        int px = max(xy.x, 0), py = max(xy.y, 0);
        int kidx = px / KK + mxk * (py / KK);
        unsigned rel = (unsigned)(kidx - lo);
        if (rel < NB) lrows[rel * K2 + (py & (KK - 1)) * KK + (px & (KK - 1))] = t + i * 256;
    }
    __syncthreads();

    const float scale = 2.1213203435596424f;  // sqrt(1152)/16
    const float4* xbase = reinterpret_cast<const float4*>(x) + (size_t)b * SS * H4;
    float4* obase = reinterpret_cast<float4*>(out) + (size_t)b * OUTL * H4;

    // ---- gather: 3 chunks, each 16 rows x 2 rep-strided float4 per thread ----
#pragma unroll
    for (int it = 0; it < 3; ++it) {
        int lidx = base + it * 256 + t;
        int bo_local = lidx / HP;
        int c = lidx - bo_local * HP;
        int rel = bo_local - lo;

        int ridx[K2];
        float w[K2];
#pragma unroll
        for (int j = 0; j < K2; ++j) {
            int row = lrows[rel * K2 + j];
            w[j] = (row >= 0) ? 1.0f : 0.0f;
            ridx[j] = max(row, 0);
        }

        const float4* xb = xbase + c;
        float4 a0 = {0.f, 0.f, 0.f, 0.f};
        float4 a1 = {0.f, 0.f, 0.f, 0.f};
#pragma unroll
        for (int j = 0; j < K2; ++j) {
            const float4* p = xb + (size_t)ridx[j] * H4;
            float4 v0 = p[0], v1 = p[HP];
            float wj = w[j];
            a0.x = fmaf(v0.x, wj, a0.x); a0.y = fmaf(v0.y, wj, a0.y);
            a0.z = fmaf(v0.z, wj, a0.z); a0.w = fmaf(v0.w, wj, a0.w);
            a1.x = fmaf(v1.x, wj, a1.x); a1.y = fmaf(v1.y, wj, a1.y);
            a1.z = fmaf(v1.z, wj, a1.z); a1.w = fmaf(v1.w, wj, a1.w);
        }
        a0.x *= scale; a0.y *= scale; a0.z *= scale; a0.w *= scale;
        a1.x *= scale; a1.y *= scale; a1.z *= scale; a1.w *= scale;

        float4* ob = obase + (size_t)bo_local * H4 + c;
        ob[0] = a0;
        ob[HP] = a1;
    }
}

extern "C" void kernel_launch(void* const* d_in, const int* in_sizes, int n_in,
                              void* d_out, int out_size, void* d_ws, size_t ws_size,
                              hipStream_t stream) {
    const float* x = (const float*)d_in[0];
    const int* pos = (const int*)d_in[1];
    float* out = (float*)d_out;

    pool_fused<<<BB * GPB, 256, 0, stream>>>(x, pos, out);  // 768 blocks, 3/CU
}